// Round 1
// baseline (1262.407 us; speedup 1.0000x reference)
//
#include <hip/hip_runtime.h>
#include <hip/hip_bf16.h>

#define BATCH 4
#define NPTS  4096
#define KNN   16
#define DP    64
#define DM    128
#define PT_SCALE 0.08838834764831845f   // 1/sqrt(128)

// ---------------------------------------------------------------------------
// K1: exact KNN. Per query: top-16 smallest d2, ties -> smaller index
// (matches stable jax.lax.top_k on -d2). d2 computed with explicit rn ops to
// match the numpy reference bit-exactly (no fma contraction).
// Packed key = (f32 bits of d2)<<32 | j  -> single u64 compare handles ties.
// Block: 256 threads = 32 queries x 8 chunks of 512 candidates.
// ---------------------------------------------------------------------------
__global__ __launch_bounds__(256) void knn_kernel(const float* __restrict__ xyz,
                                                  int* __restrict__ idx_out) {
  __shared__ float sx[NPTS];
  __shared__ float sy[NPTS];
  __shared__ float sz[NPTS];
  __shared__ unsigned long long mbuf[32][129];  // padded row to break bank conflicts
  const int b = blockIdx.y;
  const float* xb = xyz + (size_t)b * NPTS * 3;
  for (int i = threadIdx.x; i < NPTS; i += 256) {
    sx[i] = xb[i * 3 + 0];
    sy[i] = xb[i * 3 + 1];
    sz[i] = xb[i * 3 + 2];
  }
  __syncthreads();
  const int q  = threadIdx.x & 31;   // query within block
  const int c  = threadIdx.x >> 5;   // chunk 0..7
  const int qg = blockIdx.x * 32 + q;
  const float qx = sx[qg], qy = sy[qg], qz = sz[qg];

  unsigned long long kk[16];
#pragma unroll
  for (int s = 0; s < 16; ++s) kk[s] = 0xFFFFFFFFFFFFFFFFULL;

  const int j0 = c * 512;
  for (int i = 0; i < 512; ++i) {
    const int j = j0 + i;
    const float dx = __fsub_rn(qx, sx[j]);
    const float dy = __fsub_rn(qy, sy[j]);
    const float dz = __fsub_rn(qz, sz[j]);
    const float d2 =
        __fadd_rn(__fadd_rn(__fmul_rn(dx, dx), __fmul_rn(dy, dy)), __fmul_rn(dz, dz));
    const unsigned long long key =
        ((unsigned long long)__float_as_uint(d2) << 32) | (unsigned int)j;
    bool lt[16];
#pragma unroll
    for (int s = 0; s < 16; ++s) lt[s] = key < kk[s];
#pragma unroll
    for (int s = 15; s >= 1; --s) kk[s] = lt[s] ? (lt[s - 1] ? kk[s - 1] : key) : kk[s];
    kk[0] = lt[0] ? key : kk[0];
  }
#pragma unroll
  for (int s = 0; s < 16; ++s) mbuf[q][c * 16 + s] = kk[s];
  __syncthreads();

  if (threadIdx.x < 32) {
    const int qq = threadIdx.x;
    unsigned long long mm[16];
#pragma unroll
    for (int s = 0; s < 16; ++s) mm[s] = 0xFFFFFFFFFFFFFFFFULL;
    for (int e = 0; e < 128; ++e) {
      const unsigned long long key = mbuf[qq][e];
      bool lt[16];
#pragma unroll
      for (int s = 0; s < 16; ++s) lt[s] = key < mm[s];
#pragma unroll
      for (int s = 15; s >= 1; --s) mm[s] = lt[s] ? (lt[s - 1] ? mm[s - 1] : key) : mm[s];
      mm[0] = lt[0] ? key : mm[0];
    }
    int* op = idx_out + ((size_t)b * NPTS + (size_t)blockIdx.x * 32 + qq) * KNN;
#pragma unroll
    for (int s = 0; s < 16; ++s) op[s] = (int)(mm[s] & 0xFFFFFFFFULL);
  }
}

// ---------------------------------------------------------------------------
// K2: x = features@fc1 + fc1_b ; q = x@wq ; k_full = x@wk ; v_full = x@wv
// Block: 256 threads, 16 rows. x kept in LDS only.
// ---------------------------------------------------------------------------
__global__ __launch_bounds__(256) void qkv_kernel(
    const float* __restrict__ features,
    const float* __restrict__ fc1_w, const float* __restrict__ fc1_b,
    const float* __restrict__ wq, const float* __restrict__ wk, const float* __restrict__ wv,
    float* __restrict__ q_full, float* __restrict__ k_full, float* __restrict__ v_full) {
  __shared__ float feat_s[16][DP];
  __shared__ float x_s[16][DM];
  const size_t row0 = (size_t)blockIdx.x * 16;

  for (int i = threadIdx.x; i < 16 * DP; i += 256)
    feat_s[i >> 6][i & 63] = features[row0 * DP + i];
  __syncthreads();

  const int col = threadIdx.x & 127;
  const int rg  = (threadIdx.x >> 7) * 8;   // rows rg..rg+7
  {
    float acc[8];
    const float bias = fc1_b[col];
#pragma unroll
    for (int r = 0; r < 8; ++r) acc[r] = bias;
    for (int k = 0; k < DP; ++k) {
      const float w = fc1_w[k * DM + col];
#pragma unroll
      for (int r = 0; r < 8; ++r) acc[r] = fmaf(feat_s[rg + r][k], w, acc[r]);
    }
#pragma unroll
    for (int r = 0; r < 8; ++r) x_s[rg + r][col] = acc[r];
  }
  __syncthreads();

  const float* Ws[3] = {wq, wk, wv};
  float* Os[3] = {q_full, k_full, v_full};
#pragma unroll
  for (int m = 0; m < 3; ++m) {
    const float* W = Ws[m];
    float acc[8];
#pragma unroll
    for (int r = 0; r < 8; ++r) acc[r] = 0.f;
    for (int k = 0; k < DM; ++k) {
      const float w = W[k * DM + col];
#pragma unroll
      for (int r = 0; r < 8; ++r) acc[r] = fmaf(x_s[rg + r][k], w, acc[r]);
    }
    float* O = Os[m] + row0 * DM;
#pragma unroll
    for (int r = 0; r < 8; ++r) O[(rg + r) * DM + col] = acc[r];
  }
}

// ---------------------------------------------------------------------------
// K3: pos_enc = relu(rel@d1 + d1_b)@d2 + d2_b   -> written to d_out attn
// region (used as scratch; gamma kernel overwrites it in place with attn).
// Block: 256 threads, 32 queries, d2 staged in LDS (f32, 64KB).
// ---------------------------------------------------------------------------
__global__ __launch_bounds__(256) void posenc_kernel(
    const float* __restrict__ xyz, const int* __restrict__ idx_ws,
    const float* __restrict__ d1_w, const float* __restrict__ d1_b,
    const float* __restrict__ d2_w, const float* __restrict__ d2_b,
    float* __restrict__ pos_out) {
  __shared__ __align__(16) float d2_s[DM][DM];
  __shared__ float d1_s[3][DM];
  __shared__ float d1b_s[DM];
  __shared__ float d2b_s[DM];
  __shared__ float t1_s[16][DM];
  __shared__ float rel_s[16][3];

  for (int i = threadIdx.x; i < DM * DM; i += 256) d2_s[i >> 7][i & 127] = d2_w[i];
  for (int i = threadIdx.x; i < 3 * DM; i += 256) d1_s[i >> 7][i & 127] = d1_w[i];
  if (threadIdx.x < DM) {
    d1b_s[threadIdx.x] = d1_b[threadIdx.x];
    d2b_s[threadIdx.x] = d2_b[threadIdx.x];
  }
  __syncthreads();

  const int tcol4 = (threadIdx.x & 31) * 4;
  const int trow  = (threadIdx.x >> 5) * 2;

  for (int qi = 0; qi < 32; ++qi) {
    const int qid = blockIdx.x * 32 + qi;
    const int b = qid >> 12;
    const int n = qid & 4095;
    if (threadIdx.x < 16) {
      const int j = idx_ws[(size_t)qid * KNN + threadIdx.x];
      const float* pq = xyz + ((size_t)b * NPTS + n) * 3;
      const float* pj = xyz + ((size_t)b * NPTS + j) * 3;
      rel_s[threadIdx.x][0] = pq[0] - pj[0];
      rel_s[threadIdx.x][1] = pq[1] - pj[1];
      rel_s[threadIdx.x][2] = pq[2] - pj[2];
    }
    __syncthreads();
    {
      const int ccol = threadIdx.x & 127;
      const int rg = (threadIdx.x >> 7) * 8;
      const float w0 = d1_s[0][ccol], w1 = d1_s[1][ccol], w2 = d1_s[2][ccol];
      const float bb = d1b_s[ccol];
#pragma unroll
      for (int r = 0; r < 8; ++r) {
        float v = fmaf(rel_s[rg + r][0], w0,
                  fmaf(rel_s[rg + r][1], w1,
                  fmaf(rel_s[rg + r][2], w2, bb)));
        t1_s[rg + r][ccol] = v > 0.f ? v : 0.f;
      }
    }
    __syncthreads();
    {
      float acc[2][4];
#pragma unroll
      for (int cc = 0; cc < 4; ++cc) {
        const float bb = d2b_s[tcol4 + cc];
        acc[0][cc] = bb;
        acc[1][cc] = bb;
      }
      for (int k = 0; k < DM; ++k) {
        const float a0 = t1_s[trow][k];
        const float a1 = t1_s[trow + 1][k];
        const float4 w = *(const float4*)&d2_s[k][tcol4];
        acc[0][0] = fmaf(a0, w.x, acc[0][0]);
        acc[0][1] = fmaf(a0, w.y, acc[0][1]);
        acc[0][2] = fmaf(a0, w.z, acc[0][2]);
        acc[0][3] = fmaf(a0, w.w, acc[0][3]);
        acc[1][0] = fmaf(a1, w.x, acc[1][0]);
        acc[1][1] = fmaf(a1, w.y, acc[1][1]);
        acc[1][2] = fmaf(a1, w.z, acc[1][2]);
        acc[1][3] = fmaf(a1, w.w, acc[1][3]);
      }
      float* po = pos_out + ((size_t)qid * KNN + trow) * DM + tcol4;
      *(float4*)&po[0]  = make_float4(acc[0][0], acc[0][1], acc[0][2], acc[0][3]);
      *(float4*)&po[DM] = make_float4(acc[1][0], acc[1][1], acc[1][2], acc[1][3]);
    }
    // no extra sync needed: next iter writes rel_s (not read in this phase),
    // and t1_s writes only happen after the next barrier.
  }
}

// ---------------------------------------------------------------------------
// K4: h = q - k_gather + pos ; attn = softmax(SCALE*(relu(h@g1+b)@g2+b), K) ;
// res = sum_k attn*(v_gather+pos) ; out = res@fc2 + fc2_b + features.
// Reads pos from the attn region, overwrites it in place with attn.
// Block: 256 threads, 16 queries, g1+g2 staged f32 in LDS (128KB).
// ---------------------------------------------------------------------------
__global__ __launch_bounds__(256) void gamma_kernel(
    const int* __restrict__ idx_ws,
    const float* __restrict__ q_full, const float* __restrict__ k_full,
    const float* __restrict__ v_full,
    const float* __restrict__ g1_w, const float* __restrict__ g1_b,
    const float* __restrict__ g2_w, const float* __restrict__ g2_b,
    const float* __restrict__ fc2_w, const float* __restrict__ fc2_b,
    const float* __restrict__ features,
    float* __restrict__ out, float* __restrict__ attn) {
  __shared__ __align__(16) float g1_s[DM][DM];
  __shared__ __align__(16) float g2_s[DM][DM];
  __shared__ float g1b_s[DM];
  __shared__ float g2b_s[DM];
  __shared__ __align__(16) float h_s[16][DM];   // h -> logits -> probs
  __shared__ __align__(16) float t_s[16][DM];
  __shared__ float qrow_s[DM];                  // q row, then res
  __shared__ int sidx[16];

  for (int i = threadIdx.x; i < DM * DM; i += 256) {
    g1_s[i >> 7][i & 127] = g1_w[i];
    g2_s[i >> 7][i & 127] = g2_w[i];
  }
  if (threadIdx.x < DM) {
    g1b_s[threadIdx.x] = g1_b[threadIdx.x];
    g2b_s[threadIdx.x] = g2_b[threadIdx.x];
  }
  __syncthreads();

  const int tcol4 = (threadIdx.x & 31) * 4;
  const int trow  = (threadIdx.x >> 5) * 2;

  for (int qi = 0; qi < 16; ++qi) {
    const int qid = blockIdx.x * 16 + qi;
    const int b = qid >> 12;
    if (threadIdx.x < DM) qrow_s[threadIdx.x] = q_full[(size_t)qid * DM + threadIdx.x];
    if (threadIdx.x < 16) sidx[threadIdx.x] = idx_ws[(size_t)qid * KNN + threadIdx.x];
    __syncthreads();

    {  // h = q - k_gather + pos
      const int ccol = threadIdx.x & 127;
      const int rg = (threadIdx.x >> 7) * 8;
      const float qv = qrow_s[ccol];
#pragma unroll
      for (int r = 0; r < 8; ++r) {
        const int krow = rg + r;
        const float kv = k_full[((size_t)b * NPTS + sidx[krow]) * DM + ccol];
        const float pv = attn[((size_t)qid * KNN + krow) * DM + ccol];
        h_s[krow][ccol] = qv - kv + pv;
      }
    }
    __syncthreads();

    {  // t = relu(h@g1 + g1_b)
      float acc[2][4];
#pragma unroll
      for (int cc = 0; cc < 4; ++cc) {
        const float bb = g1b_s[tcol4 + cc];
        acc[0][cc] = bb;
        acc[1][cc] = bb;
      }
      for (int k = 0; k < DM; ++k) {
        const float a0 = h_s[trow][k];
        const float a1 = h_s[trow + 1][k];
        const float4 w = *(const float4*)&g1_s[k][tcol4];
        acc[0][0] = fmaf(a0, w.x, acc[0][0]);
        acc[0][1] = fmaf(a0, w.y, acc[0][1]);
        acc[0][2] = fmaf(a0, w.z, acc[0][2]);
        acc[0][3] = fmaf(a0, w.w, acc[0][3]);
        acc[1][0] = fmaf(a1, w.x, acc[1][0]);
        acc[1][1] = fmaf(a1, w.y, acc[1][1]);
        acc[1][2] = fmaf(a1, w.z, acc[1][2]);
        acc[1][3] = fmaf(a1, w.w, acc[1][3]);
      }
#pragma unroll
      for (int r = 0; r < 2; ++r)
#pragma unroll
        for (int cc = 0; cc < 4; ++cc)
          t_s[trow + r][tcol4 + cc] = acc[r][cc] > 0.f ? acc[r][cc] : 0.f;
    }
    __syncthreads();

    {  // logits = t@g2 + g2_b  -> h_s
      float acc[2][4];
#pragma unroll
      for (int cc = 0; cc < 4; ++cc) {
        const float bb = g2b_s[tcol4 + cc];
        acc[0][cc] = bb;
        acc[1][cc] = bb;
      }
      for (int k = 0; k < DM; ++k) {
        const float a0 = t_s[trow][k];
        const float a1 = t_s[trow + 1][k];
        const float4 w = *(const float4*)&g2_s[k][tcol4];
        acc[0][0] = fmaf(a0, w.x, acc[0][0]);
        acc[0][1] = fmaf(a0, w.y, acc[0][1]);
        acc[0][2] = fmaf(a0, w.z, acc[0][2]);
        acc[0][3] = fmaf(a0, w.w, acc[0][3]);
        acc[1][0] = fmaf(a1, w.x, acc[1][0]);
        acc[1][1] = fmaf(a1, w.y, acc[1][1]);
        acc[1][2] = fmaf(a1, w.z, acc[1][2]);
        acc[1][3] = fmaf(a1, w.w, acc[1][3]);
      }
#pragma unroll
      for (int r = 0; r < 2; ++r)
#pragma unroll
        for (int cc = 0; cc < 4; ++cc)
          h_s[trow + r][tcol4 + cc] = acc[r][cc];
    }
    __syncthreads();

    if (threadIdx.x < DM) {  // softmax over K per channel
      const int f = threadIdx.x;
      float av[16];
#pragma unroll
      for (int k = 0; k < 16; ++k) av[k] = h_s[k][f];
      float m = av[0];
#pragma unroll
      for (int k = 1; k < 16; ++k) m = fmaxf(m, av[k]);
      float sum = 0.f;
#pragma unroll
      for (int k = 0; k < 16; ++k) {
        av[k] = __expf((av[k] - m) * PT_SCALE);
        sum += av[k];
      }
      const float inv = 1.f / sum;
#pragma unroll
      for (int k = 0; k < 16; ++k) h_s[k][f] = av[k] * inv;
    }
    __syncthreads();

    if (threadIdx.x < DM) {  // res = sum_k p * (v_gather + pos)
      const int f = threadIdx.x;
      float acc = 0.f;
#pragma unroll
      for (int k = 0; k < 16; ++k) {
        const float vv = v_full[((size_t)b * NPTS + sidx[k]) * DM + f];
        const float pv = attn[((size_t)qid * KNN + k) * DM + f];
        acc = fmaf(h_s[k][f], vv + pv, acc);
      }
      qrow_s[f] = acc;
    }
    __syncthreads();

    if (threadIdx.x < DP) {  // out = res@fc2 + fc2_b + features
      const int c2 = threadIdx.x;
      float acc = fc2_b[c2] + features[(size_t)qid * DP + c2];
      for (int f = 0; f < DM; ++f) acc = fmaf(qrow_s[f], fc2_w[f * DP + c2], acc);
      out[(size_t)qid * DP + c2] = acc;
    }
    {  // write attn (overwrites the pos scratch for this query)
      const float4* src = (const float4*)(&h_s[0][0]);
      float4* dst = (float4*)(attn + (size_t)qid * (KNN * DM));
      dst[threadIdx.x] = src[threadIdx.x];
      dst[threadIdx.x + 256] = src[threadIdx.x + 256];
    }
    __syncthreads();
  }
}

// ---------------------------------------------------------------------------
extern "C" void kernel_launch(void* const* d_in, const int* in_sizes, int n_in,
                              void* d_out, int out_size, void* d_ws, size_t ws_size,
                              hipStream_t stream) {
  (void)in_sizes; (void)n_in; (void)out_size; (void)ws_size;
  const float* xyz      = (const float*)d_in[0];
  const float* features = (const float*)d_in[1];
  const float* fc1_w = (const float*)d_in[2];
  const float* fc1_b = (const float*)d_in[3];
  const float* fc2_w = (const float*)d_in[4];
  const float* fc2_b = (const float*)d_in[5];
  const float* d1_w  = (const float*)d_in[6];
  const float* d1_b  = (const float*)d_in[7];
  const float* d2_w  = (const float*)d_in[8];
  const float* d2_b  = (const float*)d_in[9];
  const float* g1_w  = (const float*)d_in[10];
  const float* g1_b  = (const float*)d_in[11];
  const float* g2_w  = (const float*)d_in[12];
  const float* g2_b  = (const float*)d_in[13];
  const float* wq_w  = (const float*)d_in[14];
  const float* wk_w  = (const float*)d_in[15];
  const float* wv_w  = (const float*)d_in[16];

  float* out  = (float*)d_out;
  float* attn = out + (size_t)BATCH * NPTS * DP;   // also pos_enc scratch

  char* ws = (char*)d_ws;
  int*   idx_ws = (int*)ws;                          // 1 MB
  float* q_full = (float*)(ws + (1u << 20));         // 8 MB
  float* k_full = (float*)(ws + (1u << 20) + (8u << 20));
  float* v_full = (float*)(ws + (1u << 20) + (16u << 20));

  knn_kernel<<<dim3(128, BATCH), 256, 0, stream>>>(xyz, idx_ws);
  qkv_kernel<<<dim3(1024), 256, 0, stream>>>(features, fc1_w, fc1_b,
                                             wq_w, wk_w, wv_w,
                                             q_full, k_full, v_full);
  posenc_kernel<<<dim3(512), 256, 0, stream>>>(xyz, idx_ws, d1_w, d1_b,
                                               d2_w, d2_b, attn);
  gamma_kernel<<<dim3(1024), 256, 0, stream>>>(idx_ws, q_full, k_full, v_full,
                                               g1_w, g1_b, g2_w, g2_b,
                                               fc2_w, fc2_b, features, out, attn);
}

// Round 2
// 497.886 us; speedup vs baseline: 2.5355x; 2.5355x over previous
//
#include <hip/hip_runtime.h>

#define BATCH 4
#define NPTS  4096
#define KNN   16
#define DP    64
#define DM    128
#define PT_SCALE 0.08838834764831845f   // 1/sqrt(128)

typedef short bf16x8 __attribute__((ext_vector_type(8)));
typedef float f32x4 __attribute__((ext_vector_type(4)));

__device__ __forceinline__ unsigned short f2b(float f) {  // f32 -> bf16 RNE
  unsigned u = __float_as_uint(f);
  return (unsigned short)((u + 0x7FFFu + ((u >> 16) & 1u)) >> 16);
}
__device__ __forceinline__ float b2f(unsigned short u) {
  return __uint_as_float(((unsigned)u) << 16);
}

// ---------------------------------------------------------------------------
// K1: exact KNN, one wave per query. Distributed sorted top-16: slot s lives
// in lane s (ascending by u64 key = d2_bits<<32 | j, exact tie-break).
// Wave-uniform threshold (lane 15) -> ballot -> rare shfl-based inserts.
// d2 uses explicit rn ops to match numpy bit-exactly.
// ---------------------------------------------------------------------------
__global__ __launch_bounds__(256) void knn_kernel(const float* __restrict__ xyz,
                                                  int* __restrict__ idx_out) {
  const int wv = threadIdx.x >> 6, lane = threadIdx.x & 63;
  const int qid = blockIdx.x * 4 + wv;
  const int b = qid >> 12, n = qid & 4095;
  const float* xb = xyz + (size_t)b * NPTS * 3;
  const float qx = xb[n * 3 + 0], qy = xb[n * 3 + 1], qz = xb[n * 3 + 2];

  unsigned long long kk = 0xFFFFFFFFFFFFFFFFULL;
  for (int j0 = 0; j0 < NPTS; j0 += 64) {
    const int j = j0 + lane;
    const float cx = xb[j * 3 + 0], cy = xb[j * 3 + 1], cz = xb[j * 3 + 2];
    const float dx = __fsub_rn(qx, cx);
    const float dy = __fsub_rn(qy, cy);
    const float dz = __fsub_rn(qz, cz);
    const float d2 =
        __fadd_rn(__fadd_rn(__fmul_rn(dx, dx), __fmul_rn(dy, dy)), __fmul_rn(dz, dz));
    const unsigned long long key =
        ((unsigned long long)__float_as_uint(d2) << 32) | (unsigned int)j;
    const unsigned long long t = __shfl(kk, 15, 64);
    unsigned long long m = __ballot(key < t);
    while (m) {
      const int src = __ffsll((unsigned long long)m) - 1;
      m &= m - 1;
      const unsigned long long kv = __shfl(key, src, 64);
      const bool pr = kk > kv;                       // this slot shifts right
      const unsigned long long up = __shfl_up(kk, 1, 64);
      int pp = __shfl_up(pr ? 1 : 0, 1, 64);
      if (lane == 0) pp = 0;
      kk = pr ? (pp ? up : kv) : kk;                 // no-op if kv >= kk[15]
    }
  }
  if (lane < 16)
    idx_out[(size_t)qid * KNN + lane] = (int)(kk & 0xFFFFFFFFULL);
}

// ---------------------------------------------------------------------------
// K2: pack d2/g1/g2 weights (f32 [128][128], k-major) into bf16 MFMA
// B-fragment order: pk[((nt*4+ks)*64 + lane)*8 + i] = W[(lane>>4)*8+i+32*ks][nt*16+(lane&15)]
// ---------------------------------------------------------------------------
__global__ __launch_bounds__(256) void prep_kernel(const float* __restrict__ d2_w,
                                                   const float* __restrict__ g1_w,
                                                   const float* __restrict__ g2_w,
                                                   unsigned short* __restrict__ pk) {
  const float* W = blockIdx.x == 0 ? d2_w : (blockIdx.x == 1 ? g1_w : g2_w);
  unsigned short* o = pk + (size_t)blockIdx.x * 16384;
  for (int e = threadIdx.x; e < 16384; e += 256) {
    const int i = e & 7, l = (e >> 3) & 63, fr = e >> 9;
    const int nt = fr >> 2, ks = fr & 3;
    const int k = (l >> 4) * 8 + i + 32 * ks;
    const int c = nt * 16 + (l & 15);
    o[e] = f2b(W[k * DM + c]);
  }
}

// ---------------------------------------------------------------------------
// K3: x = features@fc1+b ; q/k/v = x@W -> stored bf16
// ---------------------------------------------------------------------------
__global__ __launch_bounds__(256) void qkv_kernel(
    const float* __restrict__ features,
    const float* __restrict__ fc1_w, const float* __restrict__ fc1_b,
    const float* __restrict__ wq, const float* __restrict__ wk, const float* __restrict__ wv,
    unsigned short* __restrict__ q_full, unsigned short* __restrict__ k_full,
    unsigned short* __restrict__ v_full) {
  __shared__ float feat_s[16][DP];
  __shared__ float x_s[16][DM];
  const size_t row0 = (size_t)blockIdx.x * 16;

  for (int i = threadIdx.x; i < 16 * DP; i += 256)
    feat_s[i >> 6][i & 63] = features[row0 * DP + i];
  __syncthreads();

  const int col = threadIdx.x & 127;
  const int rg  = (threadIdx.x >> 7) * 8;
  {
    float acc[8];
    const float bias = fc1_b[col];
#pragma unroll
    for (int r = 0; r < 8; ++r) acc[r] = bias;
    for (int k = 0; k < DP; ++k) {
      const float w = fc1_w[k * DM + col];
#pragma unroll
      for (int r = 0; r < 8; ++r) acc[r] = fmaf(feat_s[rg + r][k], w, acc[r]);
    }
#pragma unroll
    for (int r = 0; r < 8; ++r) x_s[rg + r][col] = acc[r];
  }
  __syncthreads();

  const float* Ws[3] = {wq, wk, wv};
  unsigned short* Os[3] = {q_full, k_full, v_full};
#pragma unroll
  for (int m = 0; m < 3; ++m) {
    const float* W = Ws[m];
    float acc[8];
#pragma unroll
    for (int r = 0; r < 8; ++r) acc[r] = 0.f;
    for (int k = 0; k < DM; ++k) {
      const float w = W[k * DM + col];
#pragma unroll
      for (int r = 0; r < 8; ++r) acc[r] = fmaf(x_s[rg + r][k], w, acc[r]);
    }
    unsigned short* O = Os[m] + row0 * DM;
#pragma unroll
    for (int r = 0; r < 8; ++r) O[(rg + r) * DM + col] = f2b(acc[r]);
  }
}

// ---------------------------------------------------------------------------
// K4: fused posenc + gamma + softmax + aggregation, one wave per query batch.
// Per query (16 nbrs x 128 ch), all MFMA 16x16x32 bf16:
//   t1 = relu(rel@d1+b)  (A-frags built in-register)
//   pos = t1@d2+b        (B-frags streamed from global pk, L1/L2-hot)
//   h = q - k_gather + pos -> LDS scratch (C-layout) -> A-frags
//   u = relu(h@g1+b) -> scratch -> A-frags ; logits = u@g2+b
//   softmax over K via 4-val in-lane + shfl_xor(16,32)
//   attn -> d_out ; res = sum_k attn*(v+pos) -> res_ws (fc2 deferred)
// ---------------------------------------------------------------------------
__global__ __launch_bounds__(512, 2) void fused_attn_kernel(
    const float* __restrict__ xyz, const int* __restrict__ idxg,
    const unsigned short* __restrict__ qf, const unsigned short* __restrict__ kf,
    const unsigned short* __restrict__ vf,
    const unsigned short* __restrict__ d2pk, const unsigned short* __restrict__ g1pk,
    const unsigned short* __restrict__ g2pk,
    const float* __restrict__ d1_w, const float* __restrict__ d1_b,
    const float* __restrict__ d2_b, const float* __restrict__ g1_b,
    const float* __restrict__ g2_b,
    float* __restrict__ attn_out, float* __restrict__ res_ws) {
  __shared__ unsigned short g1s[16384];     // 32 KB
  __shared__ unsigned short g2s[16384];     // 32 KB
  __shared__ float sc[8][16 * 132];         // 66 KB per-wave scratch (padded rows)
  __shared__ float d1s[3 * DM];
  __shared__ float d1bs[DM], d2bs[DM], g1bs[DM], g2bs[DM];

  for (int i = threadIdx.x; i < 2048; i += 512) {
    ((uint4*)g1s)[i] = ((const uint4*)g1pk)[i];
    ((uint4*)g2s)[i] = ((const uint4*)g2pk)[i];
  }
  if (threadIdx.x < 384) d1s[threadIdx.x] = d1_w[threadIdx.x];
  if (threadIdx.x < DM) {
    d1bs[threadIdx.x] = d1_b[threadIdx.x];
    d2bs[threadIdx.x] = d2_b[threadIdx.x];
    g1bs[threadIdx.x] = g1_b[threadIdx.x];
    g2bs[threadIdx.x] = g2_b[threadIdx.x];
  }
  __syncthreads();

  const int wv = threadIdx.x >> 6, lane = threadIdx.x & 63;
  const int g = lane >> 4, c15 = lane & 15;
  float* S = sc[wv];

  for (int qi = 0; qi < 8; ++qi) {
    const int qid = (blockIdx.x * 8 + wv) * 8 + qi;
    const int b = qid >> 12, n = qid & 4095;
    const size_t bN = (size_t)b * NPTS;

    // neighbor indices: lane c15 holds idx[c15]; rows for gathers via shfl
    const int myidx = idxg[(size_t)qid * KNN + c15];
    int srow[4];
#pragma unroll
    for (int i = 0; i < 4; ++i) srow[i] = __shfl(myidx, 4 * g + i, 64);

    // issue k,q gathers early (bf16)
    unsigned short kred[8][4], qred[8];
#pragma unroll
    for (int i = 0; i < 4; ++i) {
      const unsigned short* kr = kf + (bN + srow[i]) * DM;
#pragma unroll
      for (int nt = 0; nt < 8; ++nt) kred[nt][i] = kr[nt * 16 + c15];
    }
    const unsigned short* qr = qf + (size_t)qid * DM;
#pragma unroll
    for (int nt = 0; nt < 8; ++nt) qred[nt] = qr[nt * 16 + c15];

    // rel (lane's neighbor = row c15) + t1 A-frags in-register
    const float* xq = xyz + (bN + n) * 3;
    const float* xn = xyz + (bN + myidx) * 3;
    const float rx = xq[0] - xn[0], ry = xq[1] - xn[1], rz = xq[2] - xn[2];
    bf16x8 a[4];
#pragma unroll
    for (int ks = 0; ks < 4; ++ks) {
#pragma unroll
      for (int i = 0; i < 8; ++i) {
        const int cc = g * 8 + i + 32 * ks;
        float t = fmaf(rx, d1s[cc], fmaf(ry, d1s[DM + cc], fmaf(rz, d1s[2 * DM + cc], d1bs[cc])));
        a[ks][i] = (short)f2b(t > 0.f ? t : 0.f);
      }
    }
    // pos = t1@d2 + b
    f32x4 pos[8];
#pragma unroll
    for (int nt = 0; nt < 8; ++nt) {
      const float bb = d2bs[nt * 16 + c15];
      f32x4 acc = {bb, bb, bb, bb};
#pragma unroll
      for (int ks = 0; ks < 4; ++ks) {
        const bf16x8 bfr = *(const bf16x8*)(d2pk + (((nt * 4 + ks) * 64 + lane) << 3));
        acc = __builtin_amdgcn_mfma_f32_16x16x32_bf16(a[ks], bfr, acc, 0, 0, 0);
      }
      pos[nt] = acc;
    }
    // h = q - k + pos -> scratch (C-layout ownership: row 4g+i, col nt*16+c15)
#pragma unroll
    for (int nt = 0; nt < 8; ++nt) {
      const float qv = b2f(qred[nt]);
#pragma unroll
      for (int i = 0; i < 4; ++i)
        S[(4 * g + i) * 132 + nt * 16 + c15] = qv - b2f(kred[nt][i]) + pos[nt][i];
    }
    // issue v gathers now (consumed after g1/g2 -> latency hidden)
    unsigned short vred[8][4];
#pragma unroll
    for (int i = 0; i < 4; ++i) {
      const unsigned short* vr = vf + (bN + srow[i]) * DM;
#pragma unroll
      for (int nt = 0; nt < 8; ++nt) vred[nt][i] = vr[nt * 16 + c15];
    }
    // g1: A-frags from scratch (row c15)
#pragma unroll
    for (int ks = 0; ks < 4; ++ks) {
      const float* p = &S[c15 * 132 + g * 8 + 32 * ks];
      const float4 lo = *(const float4*)p, hi = *(const float4*)(p + 4);
      a[ks][0] = (short)f2b(lo.x); a[ks][1] = (short)f2b(lo.y);
      a[ks][2] = (short)f2b(lo.z); a[ks][3] = (short)f2b(lo.w);
      a[ks][4] = (short)f2b(hi.x); a[ks][5] = (short)f2b(hi.y);
      a[ks][6] = (short)f2b(hi.z); a[ks][7] = (short)f2b(hi.w);
    }
#pragma unroll
    for (int nt = 0; nt < 8; ++nt) {
      const float bb = g1bs[nt * 16 + c15];
      f32x4 acc = {bb, bb, bb, bb};
#pragma unroll
      for (int ks = 0; ks < 4; ++ks) {
        const bf16x8 bfr = *(const bf16x8*)&g1s[((nt * 4 + ks) * 64 + lane) << 3];
        acc = __builtin_amdgcn_mfma_f32_16x16x32_bf16(a[ks], bfr, acc, 0, 0, 0);
      }
#pragma unroll
      for (int i = 0; i < 4; ++i)
        S[(4 * g + i) * 132 + nt * 16 + c15] = acc[i] > 0.f ? acc[i] : 0.f;
    }
    // g2: logits
#pragma unroll
    for (int ks = 0; ks < 4; ++ks) {
      const float* p = &S[c15 * 132 + g * 8 + 32 * ks];
      const float4 lo = *(const float4*)p, hi = *(const float4*)(p + 4);
      a[ks][0] = (short)f2b(lo.x); a[ks][1] = (short)f2b(lo.y);
      a[ks][2] = (short)f2b(lo.z); a[ks][3] = (short)f2b(lo.w);
      a[ks][4] = (short)f2b(hi.x); a[ks][5] = (short)f2b(hi.y);
      a[ks][6] = (short)f2b(hi.z); a[ks][7] = (short)f2b(hi.w);
    }
    f32x4 lg[8];
#pragma unroll
    for (int nt = 0; nt < 8; ++nt) {
      const float bb = g2bs[nt * 16 + c15];
      f32x4 acc = {bb, bb, bb, bb};
#pragma unroll
      for (int ks = 0; ks < 4; ++ks) {
        const bf16x8 bfr = *(const bf16x8*)&g2s[((nt * 4 + ks) * 64 + lane) << 3];
        acc = __builtin_amdgcn_mfma_f32_16x16x32_bf16(a[ks], bfr, acc, 0, 0, 0);
      }
      lg[nt] = acc;
    }
    // softmax over K (16 rows spread over 4 in-lane vals x lane groups ^16,^32)
#pragma unroll
    for (int nt = 0; nt < 8; ++nt) {
      float s0 = lg[nt][0] * PT_SCALE, s1 = lg[nt][1] * PT_SCALE;
      float s2 = lg[nt][2] * PT_SCALE, s3 = lg[nt][3] * PT_SCALE;
      float mx = fmaxf(fmaxf(s0, s1), fmaxf(s2, s3));
      mx = fmaxf(mx, __shfl_xor(mx, 16, 64));
      mx = fmaxf(mx, __shfl_xor(mx, 32, 64));
      const float e0 = __expf(s0 - mx), e1 = __expf(s1 - mx);
      const float e2 = __expf(s2 - mx), e3 = __expf(s3 - mx);
      float sm = e0 + e1 + e2 + e3;
      sm += __shfl_xor(sm, 16, 64);
      sm += __shfl_xor(sm, 32, 64);
      const float inv = 1.f / sm;
      lg[nt][0] = e0 * inv; lg[nt][1] = e1 * inv;
      lg[nt][2] = e2 * inv; lg[nt][3] = e3 * inv;
    }
    // attn store + res = sum_k attn*(v+pos)
    float* ab = attn_out + (size_t)qid * (KNN * DM);
    float red[8];
#pragma unroll
    for (int nt = 0; nt < 8; ++nt) {
      float r4 = 0.f;
#pragma unroll
      for (int i = 0; i < 4; ++i) {
        const float pp = lg[nt][i];
        ab[(4 * g + i) * DM + nt * 16 + c15] = pp;
        r4 = fmaf(pp, b2f(vred[nt][i]) + pos[nt][i], r4);
      }
      r4 += __shfl_xor(r4, 16, 64);
      r4 += __shfl_xor(r4, 32, 64);
      red[nt] = r4;
    }
    if (g == 0) {
      float* rw = res_ws + (size_t)qid * DM;
#pragma unroll
      for (int nt = 0; nt < 8; ++nt) rw[nt * 16 + c15] = red[nt];
    }
  }
}

// ---------------------------------------------------------------------------
// K5: out = res@fc2 + fc2_b + features   (f32, 268 MFLOP, trivial)
// ---------------------------------------------------------------------------
__global__ __launch_bounds__(256) void out_kernel(
    const float* __restrict__ res, const float* __restrict__ fc2_w,
    const float* __restrict__ fc2_b, const float* __restrict__ feat,
    float* __restrict__ out) {
  __shared__ float rs[16][DM];
  const size_t row0 = (size_t)blockIdx.x * 16;
  for (int i = threadIdx.x; i < 16 * DM; i += 256)
    rs[i >> 7][i & 127] = res[row0 * DM + i];
  __syncthreads();
  const int col = threadIdx.x & 63;
  const int rg  = (threadIdx.x >> 6) * 4;
  float acc[4];
  const float bb = fc2_b[col];
#pragma unroll
  for (int r = 0; r < 4; ++r) acc[r] = bb + feat[(row0 + rg + r) * DP + col];
  for (int k = 0; k < DM; ++k) {
    const float w = fc2_w[k * DP + col];
#pragma unroll
    for (int r = 0; r < 4; ++r) acc[r] = fmaf(rs[rg + r][k], w, acc[r]);
  }
#pragma unroll
  for (int r = 0; r < 4; ++r) out[(row0 + rg + r) * DP + col] = acc[r];
}

// ---------------------------------------------------------------------------
extern "C" void kernel_launch(void* const* d_in, const int* in_sizes, int n_in,
                              void* d_out, int out_size, void* d_ws, size_t ws_size,
                              hipStream_t stream) {
  (void)in_sizes; (void)n_in; (void)out_size; (void)ws_size;
  const float* xyz      = (const float*)d_in[0];
  const float* features = (const float*)d_in[1];
  const float* fc1_w = (const float*)d_in[2];
  const float* fc1_b = (const float*)d_in[3];
  const float* fc2_w = (const float*)d_in[4];
  const float* fc2_b = (const float*)d_in[5];
  const float* d1_w  = (const float*)d_in[6];
  const float* d1_b  = (const float*)d_in[7];
  const float* d2_w  = (const float*)d_in[8];
  const float* d2_b  = (const float*)d_in[9];
  const float* g1_w  = (const float*)d_in[10];
  const float* g1_b  = (const float*)d_in[11];
  const float* g2_w  = (const float*)d_in[12];
  const float* g2_b  = (const float*)d_in[13];
  const float* wq_w  = (const float*)d_in[14];
  const float* wk_w  = (const float*)d_in[15];
  const float* wv_w  = (const float*)d_in[16];

  float* out  = (float*)d_out;
  float* attn = out + (size_t)BATCH * NPTS * DP;

  char* ws = (char*)d_ws;
  int*            idx_ws = (int*)ws;                             // 1 MB
  unsigned short* q_full = (unsigned short*)(ws + (1u << 20));   // 4 MB each
  unsigned short* k_full = (unsigned short*)(ws + (5u << 20));
  unsigned short* v_full = (unsigned short*)(ws + (9u << 20));
  float*          res_ws = (float*)(ws + (13u << 20));           // 8 MB
  unsigned short* pk     = (unsigned short*)(ws + (21u << 20));  // 96 KB

  prep_kernel<<<dim3(3), 256, 0, stream>>>(d2_w, g1_w, g2_w, pk);
  knn_kernel<<<dim3(4096), 256, 0, stream>>>(xyz, idx_ws);
  qkv_kernel<<<dim3(1024), 256, 0, stream>>>(features, fc1_w, fc1_b,
                                             wq_w, wk_w, wv_w,
                                             q_full, k_full, v_full);
  fused_attn_kernel<<<dim3(256), 512, 0, stream>>>(
      xyz, idx_ws, q_full, k_full, v_full, pk, pk + 16384, pk + 32768,
      d1_w, d1_b, d2_b, g1_b, g2_b, attn, res_ws);
  out_kernel<<<dim3(1024), 256, 0, stream>>>(res_ws, fc2_w, fc2_b, features, out);
}